// Round 3
// baseline (3569.501 us; speedup 1.0000x reference)
//
#include <hip/hip_runtime.h>
#include <math.h>

#define N_NODES 250000
#define N_EDGES 2500000
#define N_GRAPHS 512
#define BN_EPS 1e-5f
#define NT 500000   // 2*N_NODES degree/offset slots (F then B)

// ================= CSR build (per call; ws is re-poisoned every launch) =====

__global__ void k_deg(const int* __restrict__ src, const int* __restrict__ dst,
                      int* __restrict__ deg, int E)
{
    int e = blockIdx.x * blockDim.x + threadIdx.x;
    if (e >= E) return;
    atomicAdd(&deg[dst[e]], 1);            // F lists keyed by dst
    atomicAdd(&deg[N_NODES + src[e]], 1);  // B lists keyed by src
}

// block-level exclusive scan: 1024 elems/block (256 thr x 4)
__global__ void scan1(const int* __restrict__ deg, int* __restrict__ excl,
                      int* __restrict__ bsum, int n)
{
    __shared__ int s[256];
    int t = threadIdx.x, b = blockIdx.x;
    int base = b * 1024 + t * 4;
    int v[4]; int tsum = 0;
    #pragma unroll
    for (int i = 0; i < 4; i++) { v[i] = (base + i < n) ? deg[base + i] : 0; tsum += v[i]; }
    s[t] = tsum; __syncthreads();
    for (int o = 1; o < 256; o <<= 1) {
        int x = (t >= o) ? s[t - o] : 0; __syncthreads();
        s[t] += x; __syncthreads();
    }
    int run = s[t] - tsum;  // exclusive prefix of this thread's chunk
    #pragma unroll
    for (int i = 0; i < 4; i++) { if (base + i < n) excl[base + i] = run; run += v[i]; }
    if (t == 255) bsum[b] = s[255];
}

__global__ void scan2(const int* __restrict__ bsum, int* __restrict__ boff, int nb)
{
    __shared__ int s[512];
    int t = threadIdx.x;
    int v = (t < nb) ? bsum[t] : 0;
    s[t] = v; __syncthreads();
    for (int o = 1; o < 512; o <<= 1) {
        int x = (t >= o) ? s[t - o] : 0; __syncthreads();
        s[t] += x; __syncthreads();
    }
    if (t < nb) boff[t] = s[t] - v;
}

__global__ void scan3(const int* __restrict__ excl, const int* __restrict__ boff,
                      int* __restrict__ off, int n)
{
    int i = blockIdx.x * blockDim.x + threadIdx.x;
    if (i < n) off[i] = excl[i] + boff[i >> 10];
    if (i == 0) off[n] = 2 * N_EDGES;
}

__global__ void k_fill(const int* __restrict__ src, const int* __restrict__ dst,
                       const int* __restrict__ off, int* __restrict__ cur,
                       int* __restrict__ eidx, int E)
{
    int e = blockIdx.x * blockDim.x + threadIdx.x;
    if (e >= E) return;
    int s = src[e], d = dst[e];
    int pF = atomicAdd(&cur[d], 1);
    eidx[off[d] + pF] = s;
    int pB = atomicAdd(&cur[N_NODES + s], 1);
    eidx[off[N_NODES + s] + pB] = d;
}

// ============ fused per-layer: CSR gather (both dirs) + dual GIN MLP + BN stats

template <int DIN>
__global__ __launch_bounds__(256, 2)
void dgin_fused(const float* __restrict__ xin,
                const int* __restrict__ off, const int* __restrict__ eidx,
                const float* __restrict__ W1f, const float* __restrict__ b1f,
                const float* __restrict__ W2f, const float* __restrict__ b2f,
                const float* __restrict__ W1b, const float* __restrict__ b1b,
                const float* __restrict__ W2b, const float* __restrict__ b2b,
                float* __restrict__ out, float* __restrict__ stats, int n)
{
    __shared__ __align__(16) float sW1f[DIN * 32];
    __shared__ __align__(16) float sW2f[32 * 32];
    __shared__ __align__(16) float sW1b[DIN * 32];
    __shared__ __align__(16) float sW2b[32 * 32];
    __shared__ float sb1f[32], sb2f[32], sb1b[32], sb2b[32];
    __shared__ float sred[4 * 64];

    int tid = threadIdx.x;
    for (int i = tid; i < DIN * 32; i += 256) { sW1f[i] = W1f[i]; sW1b[i] = W1b[i]; }
    for (int i = tid; i < 32 * 32;  i += 256) { sW2f[i] = W2f[i]; sW2b[i] = W2b[i]; }
    if (tid < 32) { sb1f[tid] = b1f[tid]; sb2f[tid] = b2f[tid]; sb1b[tid] = b1b[tid]; sb2b[tid] = b2b[tid]; }
    __syncthreads();

    int n0 = blockIdx.x * 256 + tid;
    bool valid = (n0 < n);
    int node = valid ? n0 : (n - 1);

    // self row (kept in regs; reused by both directions)
    float xr[DIN];
    if (DIN == 32) {
        const float4* xp = (const float4*)(xin + node * 32);
        #pragma unroll
        for (int q = 0; q < 8; q++) {
            float4 w = xp[q];
            xr[4*q+0] = w.x; xr[4*q+1] = w.y; xr[4*q+2] = w.z; xr[4*q+3] = w.w;
        }
    } else {
        const float2* xp = (const float2*)(xin + node * DIN);
        #pragma unroll
        for (int q = 0; q < DIN / 2; q++) {
            float2 w = xp[q];
            xr[2*q+0] = w.x; xr[2*q+1] = w.y;
        }
    }

    float o[32];
    float acc[DIN];

    #pragma unroll
    for (int dir = 0; dir < 2; dir++) {
        // ---- gather: acc = x + sum_{j in list} x[j]
        #pragma unroll
        for (int i = 0; i < DIN; i++) acc[i] = xr[i];
        int k0 = off[dir == 0 ? node : (N_NODES + node)];
        int k1 = off[dir == 0 ? (node + 1) : (N_NODES + node + 1)];
        int j = (k0 < k1) ? eidx[k0] : 0;
        for (int k = k0; k < k1; k++) {
            int jn = (k + 1 < k1) ? eidx[k + 1] : 0;  // prefetch next index
            if (DIN == 32) {
                const float4* rp = (const float4*)(xin + j * 32);
                #pragma unroll
                for (int q = 0; q < 8; q++) {
                    float4 w = rp[q];
                    acc[4*q+0] += w.x; acc[4*q+1] += w.y;
                    acc[4*q+2] += w.z; acc[4*q+3] += w.w;
                }
            } else {
                const float2* rp = (const float2*)(xin + j * DIN);
                #pragma unroll
                for (int q = 0; q < DIN / 2; q++) {
                    float2 w = rp[q];
                    acc[2*q+0] += w.x; acc[2*q+1] += w.y;
                }
            }
            j = jn;
        }

        // ---- 2-layer MLP on acc
        const float* sW1 = dir == 0 ? sW1f : sW1b;
        const float* sW2 = dir == 0 ? sW2f : sW2b;
        const float* sb1 = dir == 0 ? sb1f : sb1b;
        const float* sb2 = dir == 0 ? sb2f : sb2b;

        float t1[32];
        #pragma unroll
        for (int jj = 0; jj < 32; jj++) t1[jj] = sb1[jj];
        #pragma unroll
        for (int i = 0; i < DIN; i++) {
            float hv = acc[i];
            const float4* wr = (const float4*)(&sW1[i * 32]);
            #pragma unroll
            for (int q = 0; q < 8; q++) {
                float4 w = wr[q];
                t1[4*q+0] += hv * w.x; t1[4*q+1] += hv * w.y;
                t1[4*q+2] += hv * w.z; t1[4*q+3] += hv * w.w;
            }
        }
        #pragma unroll
        for (int jj = 0; jj < 32; jj++) t1[jj] = fmaxf(t1[jj], 0.f);

        float o2[32];
        #pragma unroll
        for (int jj = 0; jj < 32; jj++) o2[jj] = sb2[jj];
        #pragma unroll
        for (int i = 0; i < 32; i++) {
            float hv = t1[i];
            const float4* wr = (const float4*)(&sW2[i * 32]);
            #pragma unroll
            for (int q = 0; q < 8; q++) {
                float4 w = wr[q];
                o2[4*q+0] += hv * w.x; o2[4*q+1] += hv * w.y;
                o2[4*q+2] += hv * w.z; o2[4*q+3] += hv * w.w;
            }
        }
        if (dir == 0) {
            #pragma unroll
            for (int jj = 0; jj < 32; jj++) o[jj] = fmaxf(o2[jj], 0.f);
        } else {
            #pragma unroll
            for (int jj = 0; jj < 32; jj++) o[jj] = 0.5f * (o[jj] + fmaxf(o2[jj], 0.f));
        }
    }

    if (valid) {
        float4* op = (float4*)(out + node * 32);
        #pragma unroll
        for (int q = 0; q < 8; q++)
            op[q] = make_float4(o[4*q+0], o[4*q+1], o[4*q+2], o[4*q+3]);
    }

    // ---- BN stats: wave shuffle -> cross-wave LDS -> 64 atomics per block
    int lane = tid & 63;
    int wave = tid >> 6;
    #pragma unroll
    for (int f = 0; f < 32; f++) {
        float v = valid ? o[f] : 0.f;
        float v2 = v * v;
        #pragma unroll
        for (int offs = 32; offs > 0; offs >>= 1) {
            v  += __shfl_down(v, offs);
            v2 += __shfl_down(v2, offs);
        }
        if (lane == 0) {
            sred[wave * 64 + f]      = v;
            sred[wave * 64 + 32 + f] = v2;
        }
    }
    __syncthreads();
    if (tid < 64) {
        float a = sred[tid] + sred[64 + tid] + sred[128 + tid] + sred[192 + tid];
        atomicAdd(&stats[tid], a);
    }
}

// ================= batch-norm normalization (in-place on layer output) ======

__global__ void bn_normalize(float* __restrict__ h, const float* __restrict__ stats,
                             const float* __restrict__ gamma, const float* __restrict__ beta, int n)
{
    __shared__ float sscale[32], sshift[32];
    int tid = threadIdx.x;
    if (tid < 32) {
        float inv_n = 1.0f / (float)n;
        float mu  = stats[tid] * inv_n;
        float var = stats[32 + tid] * inv_n - mu * mu;
        float sc  = gamma[tid] * rsqrtf(var + BN_EPS);
        sscale[tid] = sc;
        sshift[tid] = beta[tid] - mu * sc;
    }
    __syncthreads();
    int i4 = blockIdx.x * blockDim.x + tid;
    if (i4 < n * 8) {
        float4* hp = (float4*)h;
        float4 v = hp[i4];
        int f = (i4 * 4) & 31;
        v.x = v.x * sscale[f+0] + sshift[f+0];
        v.y = v.y * sscale[f+1] + sshift[f+1];
        v.z = v.z * sscale[f+2] + sshift[f+2];
        v.w = v.w * sscale[f+3] + sshift[f+3];
        hp[i4] = v;
    }
}

// ================= segmented mean-pool (batch is sorted) + head =============

__global__ void pool_seg(const float* __restrict__ h, const int* __restrict__ batch,
                         float* __restrict__ psum, float* __restrict__ pcnt, int n)
{
    int tid = threadIdx.x;
    int grp = tid >> 5, f = tid & 31;
    int base = blockIdx.x * 256;
    float acc = 0.f, cnt = 0.f;
    int curg = -1;
    for (int it = 0; it < 32; it++) {
        int nd = base + grp + it * 8;
        if (nd < n) {
            int g = batch[nd];
            if (g != curg) {
                if (curg >= 0) {
                    atomicAdd(&psum[curg * 32 + f], acc);
                    if (f == 0) atomicAdd(&pcnt[curg], cnt);
                }
                curg = g; acc = 0.f; cnt = 0.f;
            }
            acc += h[nd * 32 + f];
            cnt += 1.f;
        }
    }
    if (curg >= 0) {
        atomicAdd(&psum[curg * 32 + f], acc);
        if (f == 0) atomicAdd(&pcnt[curg], cnt);
    }
}

__global__ void head_kernel(const float* __restrict__ psum, const float* __restrict__ pcnt,
                            const float* __restrict__ lbW, const float* __restrict__ lbb,
                            const float* __restrict__ lmW, const float* __restrict__ lmb,
                            float* __restrict__ out)
{
    int g = threadIdx.x;  // 512 threads, one block
    float cnt = fmaxf(pcnt[g], 1.0f);
    float inv = 1.0f / cnt;
    float p[32];
    #pragma unroll
    for (int i = 0; i < 32; i++) p[i] = psum[g * 32 + i] * inv;
    float z = lmb[0];
    #pragma unroll
    for (int k = 0; k < 16; k++) {
        float a = lbb[k];
        #pragma unroll
        for (int i = 0; i < 32; i++) a += p[i] * lbW[i * 16 + k];
        z += fmaxf(a, 0.0f) * lmW[k];
    }
    out[g] = 1.0f / (1.0f + expf(-z));
}

// ================= launcher =================================================

extern "C" void kernel_launch(void* const* d_in, const int* in_sizes, int n_in,
                              void* d_out, int out_size, void* d_ws, size_t ws_size,
                              hipStream_t stream)
{
    const float* x   = (const float*)d_in[0];
    const int* ei    = (const int*)d_in[1];
    const int* batch = (const int*)d_in[2];
    const int* src = ei;
    const int* dst = ei + N_EDGES;

    char* ws = (char*)d_ws;
    float* h_a   = (float*)(ws + 0);           // 32,000,000 B
    float* h_b   = (float*)(ws + 32000000);    // 32,000,000 B
    int*   eidx  = (int*)  (ws + 64000000);    // 20,000,000 B
    int*   off   = (int*)  (ws + 84000000);    // 2,000,004 B (NT+1 ints)
    int*   deg   = (int*)  (ws + 86000016);    // 2,000,000 B
    int*   cur   = (int*)  (ws + 88000016);    // 2,000,000 B
    int*   excl  = (int*)  (ws + 90000016);    // 2,000,000 B
    int*   bsum  = (int*)  (ws + 92000016);    // ~2 KB
    int*   boff  = (int*)  (ws + 92004016);    // ~2 KB
    float* stats = (float*)(ws + 92008016);    // 64 floats
    float* psum  = (float*)(ws + 92008528);    // 512*32 floats
    float* pcnt  = (float*)(ws + 92074064);    // 512 floats

    auto W = [&](int l, int j) { return (const float*)d_in[3 + (l - 1) * 10 + j]; };

    // ---- CSR build (both directions concatenated)
    hipMemsetAsync(deg, 0, NT * 4, stream);
    hipMemsetAsync(cur, 0, NT * 4, stream);
    k_deg<<<(N_EDGES + 255) / 256, 256, 0, stream>>>(src, dst, deg, N_EDGES);
    int nb = (NT + 1023) / 1024;  // 489
    scan1<<<nb, 256, 0, stream>>>(deg, excl, bsum, NT);
    scan2<<<1, 512, 0, stream>>>(bsum, boff, nb);
    scan3<<<(NT + 256) / 256, 256, 0, stream>>>(excl, boff, off, NT);
    k_fill<<<(N_EDGES + 255) / 256, 256, 0, stream>>>(src, dst, off, cur, eidx, N_EDGES);

    const int GRID_N = (N_NODES + 255) / 256;   // 977
    const int GRID_BN = (N_NODES * 8 + 255) / 256;

    // ---- layer 1 (DIN=6): x -> h_a
    hipMemsetAsync(stats, 0, 64 * 4, stream);
    dgin_fused<6><<<GRID_N, 256, 0, stream>>>(
        x, off, eidx,
        W(1,0), W(1,1), W(1,2), W(1,3), W(1,4), W(1,5), W(1,6), W(1,7),
        h_a, stats, N_NODES);
    bn_normalize<<<GRID_BN, 256, 0, stream>>>(h_a, stats, W(1,8), W(1,9), N_NODES);

    // ---- layer 2: h_a -> h_b
    hipMemsetAsync(stats, 0, 64 * 4, stream);
    dgin_fused<32><<<GRID_N, 256, 0, stream>>>(
        h_a, off, eidx,
        W(2,0), W(2,1), W(2,2), W(2,3), W(2,4), W(2,5), W(2,6), W(2,7),
        h_b, stats, N_NODES);
    bn_normalize<<<GRID_BN, 256, 0, stream>>>(h_b, stats, W(2,8), W(2,9), N_NODES);

    // ---- layer 3: h_b -> h_a
    hipMemsetAsync(stats, 0, 64 * 4, stream);
    dgin_fused<32><<<GRID_N, 256, 0, stream>>>(
        h_b, off, eidx,
        W(3,0), W(3,1), W(3,2), W(3,3), W(3,4), W(3,5), W(3,6), W(3,7),
        h_a, stats, N_NODES);
    bn_normalize<<<GRID_BN, 256, 0, stream>>>(h_a, stats, W(3,8), W(3,9), N_NODES);

    // ---- pool + head
    hipMemsetAsync(psum, 0, (size_t)N_GRAPHS * 32 * 4, stream);
    hipMemsetAsync(pcnt, 0, (size_t)N_GRAPHS * 4, stream);
    pool_seg<<<GRID_N, 256, 0, stream>>>(h_a, batch, psum, pcnt, N_NODES);
    head_kernel<<<1, 512, 0, stream>>>(psum, pcnt,
        (const float*)d_in[33], (const float*)d_in[34],
        (const float*)d_in[35], (const float*)d_in[36],
        (float*)d_out);
}

// Round 4
// 3440.387 us; speedup vs baseline: 1.0375x; 1.0375x over previous
//
#include <hip/hip_runtime.h>
#include <math.h>

#define N_NODES 250000
#define N_EDGES 2500000
#define N_GRAPHS 512
#define BN_EPS 1e-5f
#define NT 500000   // 2*N_NODES degree/offset slots (F then B)

// ================= CSR build (per call; ws is re-poisoned every launch) =====

__global__ void k_deg(const int* __restrict__ src, const int* __restrict__ dst,
                      int* __restrict__ deg, int E)
{
    int e = blockIdx.x * blockDim.x + threadIdx.x;
    if (e >= E) return;
    atomicAdd(&deg[dst[e]], 1);            // F lists keyed by dst
    atomicAdd(&deg[N_NODES + src[e]], 1);  // B lists keyed by src
}

// block-level exclusive scan: 1024 elems/block (256 thr x 4)
__global__ void scan1(const int* __restrict__ deg, int* __restrict__ excl,
                      int* __restrict__ bsum, int n)
{
    __shared__ int s[256];
    int t = threadIdx.x, b = blockIdx.x;
    int base = b * 1024 + t * 4;
    int v[4]; int tsum = 0;
    #pragma unroll
    for (int i = 0; i < 4; i++) { v[i] = (base + i < n) ? deg[base + i] : 0; tsum += v[i]; }
    s[t] = tsum; __syncthreads();
    for (int o = 1; o < 256; o <<= 1) {
        int x = (t >= o) ? s[t - o] : 0; __syncthreads();
        s[t] += x; __syncthreads();
    }
    int run = s[t] - tsum;  // exclusive prefix of this thread's chunk
    #pragma unroll
    for (int i = 0; i < 4; i++) { if (base + i < n) excl[base + i] = run; run += v[i]; }
    if (t == 255) bsum[b] = s[255];
}

__global__ void scan2(const int* __restrict__ bsum, int* __restrict__ boff, int nb)
{
    __shared__ int s[512];
    int t = threadIdx.x;
    int v = (t < nb) ? bsum[t] : 0;
    s[t] = v; __syncthreads();
    for (int o = 1; o < 512; o <<= 1) {
        int x = (t >= o) ? s[t - o] : 0; __syncthreads();
        s[t] += x; __syncthreads();
    }
    if (t < nb) boff[t] = s[t] - v;
}

__global__ void scan3(const int* __restrict__ excl, const int* __restrict__ boff,
                      int* __restrict__ off, int n)
{
    int i = blockIdx.x * blockDim.x + threadIdx.x;
    if (i < n) off[i] = excl[i] + boff[i >> 10];
    if (i == 0) off[n] = 2 * N_EDGES;
}

__global__ void k_fill(const int* __restrict__ src, const int* __restrict__ dst,
                       const int* __restrict__ off, int* __restrict__ cur,
                       int* __restrict__ eidx, int E)
{
    int e = blockIdx.x * blockDim.x + threadIdx.x;
    if (e >= E) return;
    int s = src[e], d = dst[e];
    int pF = atomicAdd(&cur[d], 1);
    eidx[off[d] + pF] = s;
    int pB = atomicAdd(&cur[N_NODES + s], 1);
    eidx[off[N_NODES + s] + pB] = d;
}

// ============ fused per-layer: CSR gather (both dirs) + dual GIN MLP + BN stats
// __launch_bounds__(256,1): live set is ~160+ floats (xr/acc/t1/o2/o). At
// (256,2) the allocator capped VGPRs at 128 -> ~2 GB/dispatch scratch spill
// (R3: WRITE 2.0 GB vs 34 MB ideal, 1142 us). 1 wave/EU -> up to 512 VGPRs,
// zero spill (validated in R2 on the identical-footprint dgin_mlp).

template <int DIN>
__global__ __launch_bounds__(256, 1)
void dgin_fused(const float* __restrict__ xin,
                const int* __restrict__ off, const int* __restrict__ eidx,
                const float* __restrict__ W1f, const float* __restrict__ b1f,
                const float* __restrict__ W2f, const float* __restrict__ b2f,
                const float* __restrict__ W1b, const float* __restrict__ b1b,
                const float* __restrict__ W2b, const float* __restrict__ b2b,
                float* __restrict__ out, float* __restrict__ stats, int n)
{
    __shared__ __align__(16) float sW1f[DIN * 32];
    __shared__ __align__(16) float sW2f[32 * 32];
    __shared__ __align__(16) float sW1b[DIN * 32];
    __shared__ __align__(16) float sW2b[32 * 32];
    __shared__ float sb1f[32], sb2f[32], sb1b[32], sb2b[32];
    __shared__ float sred[4 * 64];

    int tid = threadIdx.x;
    for (int i = tid; i < DIN * 32; i += 256) { sW1f[i] = W1f[i]; sW1b[i] = W1b[i]; }
    for (int i = tid; i < 32 * 32;  i += 256) { sW2f[i] = W2f[i]; sW2b[i] = W2b[i]; }
    if (tid < 32) { sb1f[tid] = b1f[tid]; sb2f[tid] = b2f[tid]; sb1b[tid] = b1b[tid]; sb2b[tid] = b2b[tid]; }
    __syncthreads();

    int n0 = blockIdx.x * 256 + tid;
    bool valid = (n0 < n);
    int node = valid ? n0 : (n - 1);

    // self row (kept in regs; reused by both directions)
    float xr[DIN];
    if (DIN == 32) {
        const float4* xp = (const float4*)(xin + node * 32);
        #pragma unroll
        for (int q = 0; q < 8; q++) {
            float4 w = xp[q];
            xr[4*q+0] = w.x; xr[4*q+1] = w.y; xr[4*q+2] = w.z; xr[4*q+3] = w.w;
        }
    } else {
        const float2* xp = (const float2*)(xin + node * DIN);
        #pragma unroll
        for (int q = 0; q < DIN / 2; q++) {
            float2 w = xp[q];
            xr[2*q+0] = w.x; xr[2*q+1] = w.y;
        }
    }

    float o[32];
    float acc[DIN];

    #pragma unroll
    for (int dir = 0; dir < 2; dir++) {
        // ---- gather: acc = x + sum_{j in list} x[j]
        #pragma unroll
        for (int i = 0; i < DIN; i++) acc[i] = xr[i];
        int k0 = off[dir == 0 ? node : (N_NODES + node)];
        int k1 = off[dir == 0 ? (node + 1) : (N_NODES + node + 1)];
        int j = (k0 < k1) ? eidx[k0] : 0;
        for (int k = k0; k < k1; k++) {
            int jn = (k + 1 < k1) ? eidx[k + 1] : 0;  // prefetch next index
            if (DIN == 32) {
                const float4* rp = (const float4*)(xin + j * 32);
                #pragma unroll
                for (int q = 0; q < 8; q++) {
                    float4 w = rp[q];
                    acc[4*q+0] += w.x; acc[4*q+1] += w.y;
                    acc[4*q+2] += w.z; acc[4*q+3] += w.w;
                }
            } else {
                const float2* rp = (const float2*)(xin + j * DIN);
                #pragma unroll
                for (int q = 0; q < DIN / 2; q++) {
                    float2 w = rp[q];
                    acc[2*q+0] += w.x; acc[2*q+1] += w.y;
                }
            }
            j = jn;
        }

        // ---- 2-layer MLP on acc
        const float* sW1 = dir == 0 ? sW1f : sW1b;
        const float* sW2 = dir == 0 ? sW2f : sW2b;
        const float* sb1 = dir == 0 ? sb1f : sb1b;
        const float* sb2 = dir == 0 ? sb2f : sb2b;

        float t1[32];
        #pragma unroll
        for (int jj = 0; jj < 32; jj++) t1[jj] = sb1[jj];
        #pragma unroll
        for (int i = 0; i < DIN; i++) {
            float hv = acc[i];
            const float4* wr = (const float4*)(&sW1[i * 32]);
            #pragma unroll
            for (int q = 0; q < 8; q++) {
                float4 w = wr[q];
                t1[4*q+0] += hv * w.x; t1[4*q+1] += hv * w.y;
                t1[4*q+2] += hv * w.z; t1[4*q+3] += hv * w.w;
            }
        }
        #pragma unroll
        for (int jj = 0; jj < 32; jj++) t1[jj] = fmaxf(t1[jj], 0.f);

        float o2[32];
        #pragma unroll
        for (int jj = 0; jj < 32; jj++) o2[jj] = sb2[jj];
        #pragma unroll
        for (int i = 0; i < 32; i++) {
            float hv = t1[i];
            const float4* wr = (const float4*)(&sW2[i * 32]);
            #pragma unroll
            for (int q = 0; q < 8; q++) {
                float4 w = wr[q];
                o2[4*q+0] += hv * w.x; o2[4*q+1] += hv * w.y;
                o2[4*q+2] += hv * w.z; o2[4*q+3] += hv * w.w;
            }
        }
        if (dir == 0) {
            #pragma unroll
            for (int jj = 0; jj < 32; jj++) o[jj] = fmaxf(o2[jj], 0.f);
        } else {
            #pragma unroll
            for (int jj = 0; jj < 32; jj++) o[jj] = 0.5f * (o[jj] + fmaxf(o2[jj], 0.f));
        }
    }

    if (valid) {
        float4* op = (float4*)(out + node * 32);
        #pragma unroll
        for (int q = 0; q < 8; q++)
            op[q] = make_float4(o[4*q+0], o[4*q+1], o[4*q+2], o[4*q+3]);
    }

    // ---- BN stats: wave shuffle -> cross-wave LDS -> 64 atomics per block
    int lane = tid & 63;
    int wave = tid >> 6;
    #pragma unroll
    for (int f = 0; f < 32; f++) {
        float v = valid ? o[f] : 0.f;
        float v2 = v * v;
        #pragma unroll
        for (int offs = 32; offs > 0; offs >>= 1) {
            v  += __shfl_down(v, offs);
            v2 += __shfl_down(v2, offs);
        }
        if (lane == 0) {
            sred[wave * 64 + f]      = v;
            sred[wave * 64 + 32 + f] = v2;
        }
    }
    __syncthreads();
    if (tid < 64) {
        float a = sred[tid] + sred[64 + tid] + sred[128 + tid] + sred[192 + tid];
        atomicAdd(&stats[tid], a);
    }
}

// ================= batch-norm normalization (in-place on layer output) ======

__global__ void bn_normalize(float* __restrict__ h, const float* __restrict__ stats,
                             const float* __restrict__ gamma, const float* __restrict__ beta, int n)
{
    __shared__ float sscale[32], sshift[32];
    int tid = threadIdx.x;
    if (tid < 32) {
        float inv_n = 1.0f / (float)n;
        float mu  = stats[tid] * inv_n;
        float var = stats[32 + tid] * inv_n - mu * mu;
        float sc  = gamma[tid] * rsqrtf(var + BN_EPS);
        sscale[tid] = sc;
        sshift[tid] = beta[tid] - mu * sc;
    }
    __syncthreads();
    int i4 = blockIdx.x * blockDim.x + tid;
    if (i4 < n * 8) {
        float4* hp = (float4*)h;
        float4 v = hp[i4];
        int f = (i4 * 4) & 31;
        v.x = v.x * sscale[f+0] + sshift[f+0];
        v.y = v.y * sscale[f+1] + sshift[f+1];
        v.z = v.z * sscale[f+2] + sshift[f+2];
        v.w = v.w * sscale[f+3] + sshift[f+3];
        hp[i4] = v;
    }
}

// ================= segmented mean-pool (batch is sorted) + head =============

__global__ void pool_seg(const float* __restrict__ h, const int* __restrict__ batch,
                         float* __restrict__ psum, float* __restrict__ pcnt, int n)
{
    int tid = threadIdx.x;
    int grp = tid >> 5, f = tid & 31;
    int base = blockIdx.x * 256;
    float acc = 0.f, cnt = 0.f;
    int curg = -1;
    for (int it = 0; it < 32; it++) {
        int nd = base + grp + it * 8;
        if (nd < n) {
            int g = batch[nd];
            if (g != curg) {
                if (curg >= 0) {
                    atomicAdd(&psum[curg * 32 + f], acc);
                    if (f == 0) atomicAdd(&pcnt[curg], cnt);
                }
                curg = g; acc = 0.f; cnt = 0.f;
            }
            acc += h[nd * 32 + f];
            cnt += 1.f;
        }
    }
    if (curg >= 0) {
        atomicAdd(&psum[curg * 32 + f], acc);
        if (f == 0) atomicAdd(&pcnt[curg], cnt);
    }
}

__global__ void head_kernel(const float* __restrict__ psum, const float* __restrict__ pcnt,
                            const float* __restrict__ lbW, const float* __restrict__ lbb,
                            const float* __restrict__ lmW, const float* __restrict__ lmb,
                            float* __restrict__ out)
{
    int g = threadIdx.x;  // 512 threads, one block
    float cnt = fmaxf(pcnt[g], 1.0f);
    float inv = 1.0f / cnt;
    float p[32];
    #pragma unroll
    for (int i = 0; i < 32; i++) p[i] = psum[g * 32 + i] * inv;
    float z = lmb[0];
    #pragma unroll
    for (int k = 0; k < 16; k++) {
        float a = lbb[k];
        #pragma unroll
        for (int i = 0; i < 32; i++) a += p[i] * lbW[i * 16 + k];
        z += fmaxf(a, 0.0f) * lmW[k];
    }
    out[g] = 1.0f / (1.0f + expf(-z));
}

// ================= launcher =================================================

extern "C" void kernel_launch(void* const* d_in, const int* in_sizes, int n_in,
                              void* d_out, int out_size, void* d_ws, size_t ws_size,
                              hipStream_t stream)
{
    const float* x   = (const float*)d_in[0];
    const int* ei    = (const int*)d_in[1];
    const int* batch = (const int*)d_in[2];
    const int* src = ei;
    const int* dst = ei + N_EDGES;

    char* ws = (char*)d_ws;
    float* h_a   = (float*)(ws + 0);           // 32,000,000 B
    float* h_b   = (float*)(ws + 32000000);    // 32,000,000 B
    int*   eidx  = (int*)  (ws + 64000000);    // 20,000,000 B
    int*   off   = (int*)  (ws + 84000000);    // 2,000,004 B (NT+1 ints)
    int*   deg   = (int*)  (ws + 86000016);    // 2,000,000 B
    int*   cur   = (int*)  (ws + 88000016);    // 2,000,000 B
    int*   excl  = (int*)  (ws + 90000016);    // 2,000,000 B
    int*   bsum  = (int*)  (ws + 92000016);    // ~2 KB
    int*   boff  = (int*)  (ws + 92004016);    // ~2 KB
    float* stats = (float*)(ws + 92008016);    // 64 floats
    float* psum  = (float*)(ws + 92008528);    // 512*32 floats
    float* pcnt  = (float*)(ws + 92074064);    // 512 floats

    auto W = [&](int l, int j) { return (const float*)d_in[3 + (l - 1) * 10 + j]; };

    // ---- CSR build (both directions concatenated)
    hipMemsetAsync(deg, 0, NT * 4, stream);
    hipMemsetAsync(cur, 0, NT * 4, stream);
    k_deg<<<(N_EDGES + 255) / 256, 256, 0, stream>>>(src, dst, deg, N_EDGES);
    int nb = (NT + 1023) / 1024;  // 489
    scan1<<<nb, 256, 0, stream>>>(deg, excl, bsum, NT);
    scan2<<<1, 512, 0, stream>>>(bsum, boff, nb);
    scan3<<<(NT + 256) / 256, 256, 0, stream>>>(excl, boff, off, NT);
    k_fill<<<(N_EDGES + 255) / 256, 256, 0, stream>>>(src, dst, off, cur, eidx, N_EDGES);

    const int GRID_N = (N_NODES + 255) / 256;   // 977
    const int GRID_BN = (N_NODES * 8 + 255) / 256;

    // ---- layer 1 (DIN=6): x -> h_a
    hipMemsetAsync(stats, 0, 64 * 4, stream);
    dgin_fused<6><<<GRID_N, 256, 0, stream>>>(
        x, off, eidx,
        W(1,0), W(1,1), W(1,2), W(1,3), W(1,4), W(1,5), W(1,6), W(1,7),
        h_a, stats, N_NODES);
    bn_normalize<<<GRID_BN, 256, 0, stream>>>(h_a, stats, W(1,8), W(1,9), N_NODES);

    // ---- layer 2: h_a -> h_b
    hipMemsetAsync(stats, 0, 64 * 4, stream);
    dgin_fused<32><<<GRID_N, 256, 0, stream>>>(
        h_a, off, eidx,
        W(2,0), W(2,1), W(2,2), W(2,3), W(2,4), W(2,5), W(2,6), W(2,7),
        h_b, stats, N_NODES);
    bn_normalize<<<GRID_BN, 256, 0, stream>>>(h_b, stats, W(2,8), W(2,9), N_NODES);

    // ---- layer 3: h_b -> h_a
    hipMemsetAsync(stats, 0, 64 * 4, stream);
    dgin_fused<32><<<GRID_N, 256, 0, stream>>>(
        h_b, off, eidx,
        W(3,0), W(3,1), W(3,2), W(3,3), W(3,4), W(3,5), W(3,6), W(3,7),
        h_a, stats, N_NODES);
    bn_normalize<<<GRID_BN, 256, 0, stream>>>(h_a, stats, W(3,8), W(3,9), N_NODES);

    // ---- pool + head
    hipMemsetAsync(psum, 0, (size_t)N_GRAPHS * 32 * 4, stream);
    hipMemsetAsync(pcnt, 0, (size_t)N_GRAPHS * 4, stream);
    pool_seg<<<GRID_N, 256, 0, stream>>>(h_a, batch, psum, pcnt, N_NODES);
    head_kernel<<<1, 512, 0, stream>>>(psum, pcnt,
        (const float*)d_in[33], (const float*)d_in[34],
        (const float*)d_in[35], (const float*)d_in[36],
        (float*)d_out);
}

// Round 5
// 2914.133 us; speedup vs baseline: 1.2249x; 1.1806x over previous
//
#include <hip/hip_runtime.h>
#include <math.h>

#define N_NODES 250000
#define N_EDGES 2500000
#define N_GRAPHS 512
#define BN_EPS 1e-5f
#define NT 500000   // 2*N_NODES degree/offset slots (F then B)

// ================= CSR build (per call; ws is re-poisoned every launch) =====

__global__ void k_deg(const int* __restrict__ src, const int* __restrict__ dst,
                      int* __restrict__ deg, int E)
{
    int e = blockIdx.x * blockDim.x + threadIdx.x;
    if (e >= E) return;
    atomicAdd(&deg[dst[e]], 1);            // F lists keyed by dst
    atomicAdd(&deg[N_NODES + src[e]], 1);  // B lists keyed by src
}

// block-level exclusive scan: 1024 elems/block (256 thr x 4)
__global__ void scan1(const int* __restrict__ deg, int* __restrict__ excl,
                      int* __restrict__ bsum, int n)
{
    __shared__ int s[256];
    int t = threadIdx.x, b = blockIdx.x;
    int base = b * 1024 + t * 4;
    int v[4]; int tsum = 0;
    #pragma unroll
    for (int i = 0; i < 4; i++) { v[i] = (base + i < n) ? deg[base + i] : 0; tsum += v[i]; }
    s[t] = tsum; __syncthreads();
    for (int o = 1; o < 256; o <<= 1) {
        int x = (t >= o) ? s[t - o] : 0; __syncthreads();
        s[t] += x; __syncthreads();
    }
    int run = s[t] - tsum;  // exclusive prefix of this thread's chunk
    #pragma unroll
    for (int i = 0; i < 4; i++) { if (base + i < n) excl[base + i] = run; run += v[i]; }
    if (t == 255) bsum[b] = s[255];
}

__global__ void scan2(const int* __restrict__ bsum, int* __restrict__ boff, int nb)
{
    __shared__ int s[512];
    int t = threadIdx.x;
    int v = (t < nb) ? bsum[t] : 0;
    s[t] = v; __syncthreads();
    for (int o = 1; o < 512; o <<= 1) {
        int x = (t >= o) ? s[t - o] : 0; __syncthreads();
        s[t] += x; __syncthreads();
    }
    if (t < nb) boff[t] = s[t] - v;
}

__global__ void scan3(const int* __restrict__ excl, const int* __restrict__ boff,
                      int* __restrict__ off, int n)
{
    int i = blockIdx.x * blockDim.x + threadIdx.x;
    if (i < n) off[i] = excl[i] + boff[i >> 10];
    if (i == 0) off[n] = 2 * N_EDGES;
}

__global__ void k_fill(const int* __restrict__ src, const int* __restrict__ dst,
                       const int* __restrict__ off, int* __restrict__ cur,
                       int* __restrict__ eidx, int E)
{
    int e = blockIdx.x * blockDim.x + threadIdx.x;
    if (e >= E) return;
    int s = src[e], d = dst[e];
    int pF = atomicAdd(&cur[d], 1);
    eidx[off[d] + pF] = s;
    int pB = atomicAdd(&cur[N_NODES + s], 1);
    eidx[off[N_NODES + s] + pB] = d;
}

// ============ fused per-layer: CSR gather + dual GIN MLP + BN stats =========
// Lane-per-feature layout: each half-wave (32 lanes) owns one node; lane f
// holds feature f as a SCALAR. Total live state ~30 VGPRs. R3/R4's
// thread-per-node design needed >256 VGPRs (arch cap) -> 1.7 GB scratch
// spill per dispatch. MLP matmuls use __shfl(.,i,32) broadcast within the
// half-wave; weight LDS reads are 2-lanes-same-address (free broadcast).

template <int DIN>
__global__ __launch_bounds__(256, 4)
void dgin_gather(const float* __restrict__ xin,
                 const int* __restrict__ off, const int* __restrict__ eidx,
                 const float* __restrict__ W1f, const float* __restrict__ b1f,
                 const float* __restrict__ W2f, const float* __restrict__ b2f,
                 const float* __restrict__ W1b, const float* __restrict__ b1b,
                 const float* __restrict__ W2b, const float* __restrict__ b2b,
                 float* __restrict__ out, float* __restrict__ stats, int ngroups)
{
    __shared__ float sW1[2][DIN * 32];
    __shared__ float sW2[2][32 * 32];
    __shared__ float sb1[2][32], sb2[2][32];
    __shared__ float sstat[64];

    int tid = threadIdx.x;
    for (int i = tid; i < DIN * 32; i += 256) { sW1[0][i] = W1f[i]; sW1[1][i] = W1b[i]; }
    for (int i = tid; i < 32 * 32;  i += 256) { sW2[0][i] = W2f[i]; sW2[1][i] = W2b[i]; }
    if (tid < 32) { sb1[0][tid] = b1f[tid]; sb1[1][tid] = b1b[tid];
                    sb2[0][tid] = b2f[tid]; sb2[1][tid] = b2b[tid]; }
    if (tid < 64) sstat[tid] = 0.f;
    __syncthreads();

    int f  = tid & 31;
    int hw = tid >> 5;          // half-wave id within block, 0..7
    float bn_s = 0.f, bn_s2 = 0.f;

    for (int grp = blockIdx.x; grp < ngroups; grp += gridDim.x) {
        int node = grp * 8 + hw;

        float xr = (DIN == 32) ? xin[node * 32 + f]
                               : ((f < DIN) ? xin[node * DIN + f] : 0.f);
        float o = 0.f;

        #pragma unroll
        for (int dir = 0; dir < 2; dir++) {
            int obase = dir * N_NODES + node;
            int k0 = off[obase];
            int k1 = off[obase + 1];

            float acc = xr;
            for (int k = k0; k < k1; k++) {
                int j = eidx[k];            // half-wave-uniform (cache broadcast)
                if (DIN == 32)      acc += xin[j * 32 + f];   // coalesced 128B row
                else if (f < DIN)   acc += xin[j * DIN + f];
            }

            // MLP layer 1: t1[f] = relu(b1[f] + sum_i acc_i * W1[i][f])
            float t1 = sb1[dir][f];
            #pragma unroll
            for (int i = 0; i < DIN; i++) {
                float hv = __shfl(acc, i, 32);
                t1 += hv * sW1[dir][i * 32 + f];
            }
            t1 = fmaxf(t1, 0.f);

            // MLP layer 2
            float o2 = sb2[dir][f];
            #pragma unroll
            for (int i = 0; i < 32; i++) {
                float hv = __shfl(t1, i, 32);
                o2 += hv * sW2[dir][i * 32 + f];
            }
            o += fmaxf(o2, 0.f);
        }
        o *= 0.5f;

        out[node * 32 + f] = o;             // coalesced
        bn_s  += o;
        bn_s2 += o * o;
    }

    // BN stats: per-lane running sums -> LDS atomics -> 64 global atomics
    atomicAdd(&sstat[f],      bn_s);
    atomicAdd(&sstat[32 + f], bn_s2);
    __syncthreads();
    if (tid < 64) atomicAdd(&stats[tid], sstat[tid]);
}

// ================= batch-norm normalization (in-place on layer output) ======

__global__ void bn_normalize(float* __restrict__ h, const float* __restrict__ stats,
                             const float* __restrict__ gamma, const float* __restrict__ beta, int n)
{
    __shared__ float sscale[32], sshift[32];
    int tid = threadIdx.x;
    if (tid < 32) {
        float inv_n = 1.0f / (float)n;
        float mu  = stats[tid] * inv_n;
        float var = stats[32 + tid] * inv_n - mu * mu;
        float sc  = gamma[tid] * rsqrtf(var + BN_EPS);
        sscale[tid] = sc;
        sshift[tid] = beta[tid] - mu * sc;
    }
    __syncthreads();
    int i4 = blockIdx.x * blockDim.x + tid;
    if (i4 < n * 8) {
        float4* hp = (float4*)h;
        float4 v = hp[i4];
        int f = (i4 * 4) & 31;
        v.x = v.x * sscale[f+0] + sshift[f+0];
        v.y = v.y * sscale[f+1] + sshift[f+1];
        v.z = v.z * sscale[f+2] + sshift[f+2];
        v.w = v.w * sscale[f+3] + sshift[f+3];
        hp[i4] = v;
    }
}

// ================= segmented mean-pool (batch is sorted) + head =============

__global__ void pool_seg(const float* __restrict__ h, const int* __restrict__ batch,
                         float* __restrict__ psum, float* __restrict__ pcnt, int n)
{
    int tid = threadIdx.x;
    int grp = tid >> 5, f = tid & 31;
    int base = blockIdx.x * 256;
    float acc = 0.f, cnt = 0.f;
    int curg = -1;
    for (int it = 0; it < 32; it++) {
        int nd = base + grp + it * 8;
        if (nd < n) {
            int g = batch[nd];
            if (g != curg) {
                if (curg >= 0) {
                    atomicAdd(&psum[curg * 32 + f], acc);
                    if (f == 0) atomicAdd(&pcnt[curg], cnt);
                }
                curg = g; acc = 0.f; cnt = 0.f;
            }
            acc += h[nd * 32 + f];
            cnt += 1.f;
        }
    }
    if (curg >= 0) {
        atomicAdd(&psum[curg * 32 + f], acc);
        if (f == 0) atomicAdd(&pcnt[curg], cnt);
    }
}

__global__ void head_kernel(const float* __restrict__ psum, const float* __restrict__ pcnt,
                            const float* __restrict__ lbW, const float* __restrict__ lbb,
                            const float* __restrict__ lmW, const float* __restrict__ lmb,
                            float* __restrict__ out)
{
    int g = threadIdx.x;  // 512 threads, one block
    float cnt = fmaxf(pcnt[g], 1.0f);
    float inv = 1.0f / cnt;
    float p[32];
    #pragma unroll
    for (int i = 0; i < 32; i++) p[i] = psum[g * 32 + i] * inv;
    float z = lmb[0];
    #pragma unroll
    for (int k = 0; k < 16; k++) {
        float a = lbb[k];
        #pragma unroll
        for (int i = 0; i < 32; i++) a += p[i] * lbW[i * 16 + k];
        z += fmaxf(a, 0.0f) * lmW[k];
    }
    out[g] = 1.0f / (1.0f + expf(-z));
}

// ================= launcher =================================================

extern "C" void kernel_launch(void* const* d_in, const int* in_sizes, int n_in,
                              void* d_out, int out_size, void* d_ws, size_t ws_size,
                              hipStream_t stream)
{
    const float* x   = (const float*)d_in[0];
    const int* ei    = (const int*)d_in[1];
    const int* batch = (const int*)d_in[2];
    const int* src = ei;
    const int* dst = ei + N_EDGES;

    char* ws = (char*)d_ws;
    float* h_a   = (float*)(ws + 0);           // 32,000,000 B
    float* h_b   = (float*)(ws + 32000000);    // 32,000,000 B
    int*   eidx  = (int*)  (ws + 64000000);    // 20,000,000 B
    int*   off   = (int*)  (ws + 84000000);    // 2,000,004 B (NT+1 ints)
    int*   deg   = (int*)  (ws + 86000016);    // 2,000,000 B
    int*   cur   = (int*)  (ws + 88000016);    // 2,000,000 B
    int*   excl  = (int*)  (ws + 90000016);    // 2,000,000 B
    int*   bsum  = (int*)  (ws + 92000016);    // ~2 KB
    int*   boff  = (int*)  (ws + 92004016);    // ~2 KB
    float* stats = (float*)(ws + 92008016);    // 64 floats
    float* psum  = (float*)(ws + 92008528);    // 512*32 floats
    float* pcnt  = (float*)(ws + 92074064);    // 512 floats

    auto W = [&](int l, int j) { return (const float*)d_in[3 + (l - 1) * 10 + j]; };

    // ---- CSR build (both directions concatenated)
    hipMemsetAsync(deg, 0, NT * 4, stream);
    hipMemsetAsync(cur, 0, NT * 4, stream);
    k_deg<<<(N_EDGES + 255) / 256, 256, 0, stream>>>(src, dst, deg, N_EDGES);
    int nb = (NT + 1023) / 1024;  // 489
    scan1<<<nb, 256, 0, stream>>>(deg, excl, bsum, NT);
    scan2<<<1, 512, 0, stream>>>(bsum, boff, nb);
    scan3<<<(NT + 256) / 256, 256, 0, stream>>>(excl, boff, off, NT);
    k_fill<<<(N_EDGES + 255) / 256, 256, 0, stream>>>(src, dst, off, cur, eidx, N_EDGES);

    const int NGROUPS = N_NODES / 8;           // 31250 (exact)
    const int GRID_G  = 2048;                  // grid-stride over node groups
    const int GRID_BN = (N_NODES * 8 + 255) / 256;

    // ---- layer 1 (DIN=6): x -> h_a
    hipMemsetAsync(stats, 0, 64 * 4, stream);
    dgin_gather<6><<<GRID_G, 256, 0, stream>>>(
        x, off, eidx,
        W(1,0), W(1,1), W(1,2), W(1,3), W(1,4), W(1,5), W(1,6), W(1,7),
        h_a, stats, NGROUPS);
    bn_normalize<<<GRID_BN, 256, 0, stream>>>(h_a, stats, W(1,8), W(1,9), N_NODES);

    // ---- layer 2: h_a -> h_b
    hipMemsetAsync(stats, 0, 64 * 4, stream);
    dgin_gather<32><<<GRID_G, 256, 0, stream>>>(
        h_a, off, eidx,
        W(2,0), W(2,1), W(2,2), W(2,3), W(2,4), W(2,5), W(2,6), W(2,7),
        h_b, stats, NGROUPS);
    bn_normalize<<<GRID_BN, 256, 0, stream>>>(h_b, stats, W(2,8), W(2,9), N_NODES);

    // ---- layer 3: h_b -> h_a
    hipMemsetAsync(stats, 0, 64 * 4, stream);
    dgin_gather<32><<<GRID_G, 256, 0, stream>>>(
        h_b, off, eidx,
        W(3,0), W(3,1), W(3,2), W(3,3), W(3,4), W(3,5), W(3,6), W(3,7),
        h_a, stats, NGROUPS);
    bn_normalize<<<GRID_BN, 256, 0, stream>>>(h_a, stats, W(3,8), W(3,9), N_NODES);

    // ---- pool + head
    hipMemsetAsync(psum, 0, (size_t)N_GRAPHS * 32 * 4, stream);
    hipMemsetAsync(pcnt, 0, (size_t)N_GRAPHS * 4, stream);
    pool_seg<<<(N_NODES + 255) / 256, 256, 0, stream>>>(h_a, batch, psum, pcnt, N_NODES);
    head_kernel<<<1, 512, 0, stream>>>(psum, pcnt,
        (const float*)d_in[33], (const float*)d_in[34],
        (const float*)d_in[35], (const float*)d_in[36],
        (float*)d_out);
}

// Round 6
// 2375.168 us; speedup vs baseline: 1.5028x; 1.2269x over previous
//
#include <hip/hip_runtime.h>
#include <math.h>

#define N_NODES 250000
#define N_EDGES 2500000
#define N_GRAPHS 512
#define BN_EPS 1e-5f
#define NT 500000   // 2*N_NODES degree/offset slots (F then B)
#define INV_N (1.0f / (float)N_NODES)

// ================= CSR build (per call; ws is re-poisoned every launch) =====

__global__ void k_deg(const int* __restrict__ src, const int* __restrict__ dst,
                      int* __restrict__ deg, int E)
{
    int e = blockIdx.x * blockDim.x + threadIdx.x;
    if (e >= E) return;
    atomicAdd(&deg[dst[e]], 1);            // F lists keyed by dst
    atomicAdd(&deg[N_NODES + src[e]], 1);  // B lists keyed by src
}

// block-level exclusive scan: 1024 elems/block (256 thr x 4)
__global__ void scan1(const int* __restrict__ deg, int* __restrict__ excl,
                      int* __restrict__ bsum, int n)
{
    __shared__ int s[256];
    int t = threadIdx.x, b = blockIdx.x;
    int base = b * 1024 + t * 4;
    int v[4]; int tsum = 0;
    #pragma unroll
    for (int i = 0; i < 4; i++) { v[i] = (base + i < n) ? deg[base + i] : 0; tsum += v[i]; }
    s[t] = tsum; __syncthreads();
    for (int o = 1; o < 256; o <<= 1) {
        int x = (t >= o) ? s[t - o] : 0; __syncthreads();
        s[t] += x; __syncthreads();
    }
    int run = s[t] - tsum;  // exclusive prefix of this thread's chunk
    #pragma unroll
    for (int i = 0; i < 4; i++) { if (base + i < n) excl[base + i] = run; run += v[i]; }
    if (t == 255) bsum[b] = s[255];
}

__global__ void scan2(const int* __restrict__ bsum, int* __restrict__ boff, int nb)
{
    __shared__ int s[512];
    int t = threadIdx.x;
    int v = (t < nb) ? bsum[t] : 0;
    s[t] = v; __syncthreads();
    for (int o = 1; o < 512; o <<= 1) {
        int x = (t >= o) ? s[t - o] : 0; __syncthreads();
        s[t] += x; __syncthreads();
    }
    if (t < nb) boff[t] = s[t] - v;
}

__global__ void scan3(const int* __restrict__ excl, const int* __restrict__ boff,
                      int* __restrict__ off, int n)
{
    int i = blockIdx.x * blockDim.x + threadIdx.x;
    if (i < n) off[i] = excl[i] + boff[i >> 10];
    if (i == 0) off[n] = 2 * N_EDGES;
}

__global__ void k_fill(const int* __restrict__ src, const int* __restrict__ dst,
                       const int* __restrict__ off, int* __restrict__ cur,
                       int* __restrict__ eidx, int E)
{
    int e = blockIdx.x * blockDim.x + threadIdx.x;
    if (e >= E) return;
    int s = src[e], d = dst[e];
    int pF = atomicAdd(&cur[d], 1);
    eidx[off[d] + pF] = s;
    int pB = atomicAdd(&cur[N_NODES + s], 1);
    eidx[off[N_NODES + s] + pB] = d;
}

// ============ fused per-layer: CSR gather + dual GIN MLP + BN stats =========
// Lane-per-feature: each half-wave (32 lanes) owns one node; lane f holds
// feature f as a scalar (~40 VGPRs live; R4's thread-per-node needed >256).
// R5 was latency-bound (1.85 TB/s eff, VALUBusy 10%): the k-loop had ~1
// outstanding row load. 4x manual unroll with independent partials -> 4 in
// flight. BN of the PREVIOUS layer is folded in algebraically:
//   sum over (deg+1) rows of (a*v+b) = a*raw_sum + (deg+1)*b
// so layers 2/3 read raw h and apply one fma; bn_normalize kernels deleted.

template <int DIN, bool BN_IN>
__global__ __launch_bounds__(256, 4)
void dgin_gather(const float* __restrict__ xin,
                 const int* __restrict__ off, const int* __restrict__ eidx,
                 const float* __restrict__ in_stats,   // prev layer raw sum/sumsq (BN_IN)
                 const float* __restrict__ in_g, const float* __restrict__ in_b,
                 const float* __restrict__ W1f, const float* __restrict__ b1f,
                 const float* __restrict__ W2f, const float* __restrict__ b2f,
                 const float* __restrict__ W1b, const float* __restrict__ b1b,
                 const float* __restrict__ W2b, const float* __restrict__ b2b,
                 float* __restrict__ out, float* __restrict__ stats, int ngroups)
{
    __shared__ float sW1[2][DIN * 32];
    __shared__ float sW2[2][32 * 32];
    __shared__ float sb1[2][32], sb2[2][32];
    __shared__ float sstat[64];

    int tid = threadIdx.x;
    for (int i = tid; i < DIN * 32; i += 256) { sW1[0][i] = W1f[i]; sW1[1][i] = W1b[i]; }
    for (int i = tid; i < 32 * 32;  i += 256) { sW2[0][i] = W2f[i]; sW2[1][i] = W2b[i]; }
    if (tid < 32) { sb1[0][tid] = b1f[tid]; sb1[1][tid] = b1b[tid];
                    sb2[0][tid] = b2f[tid]; sb2[1][tid] = b2b[tid]; }
    if (tid < 64) sstat[tid] = 0.f;
    __syncthreads();

    int f  = tid & 31;
    int hw = tid >> 5;          // half-wave id within block, 0..7

    // per-lane input-BN scale/shift (identity for layer 1)
    float scale = 1.f, shift = 0.f;
    if (BN_IN) {
        float mu  = in_stats[f] * INV_N;
        float var = in_stats[32 + f] * INV_N - mu * mu;
        scale = in_g[f] * rsqrtf(var + BN_EPS);
        shift = in_b[f] - mu * scale;
    }

    float bn_s = 0.f, bn_s2 = 0.f;

    for (int grp = blockIdx.x; grp < ngroups; grp += gridDim.x) {
        int node = grp * 8 + hw;

        float xr = (DIN == 32) ? xin[node * 32 + f]
                               : ((f < DIN) ? xin[node * DIN + f] : 0.f);
        float o = 0.f;

        #pragma unroll
        for (int dir = 0; dir < 2; dir++) {
            int obase = dir * N_NODES + node;
            int k0 = off[obase];
            int k1 = off[obase + 1];

            // raw gather with 4 independent partials (4 loads in flight)
            float r0 = 0.f, r1 = 0.f, r2 = 0.f, r3 = 0.f;
            int k = k0;
            for (; k + 4 <= k1; k += 4) {
                int j0 = eidx[k], j1 = eidx[k+1], j2 = eidx[k+2], j3 = eidx[k+3];
                if (DIN == 32) {
                    r0 += xin[j0 * 32 + f];
                    r1 += xin[j1 * 32 + f];
                    r2 += xin[j2 * 32 + f];
                    r3 += xin[j3 * 32 + f];
                } else if (f < DIN) {
                    r0 += xin[j0 * DIN + f];
                    r1 += xin[j1 * DIN + f];
                    r2 += xin[j2 * DIN + f];
                    r3 += xin[j3 * DIN + f];
                }
            }
            for (; k < k1; k++) {
                int j = eidx[k];
                if (DIN == 32)    r0 += xin[j * 32 + f];
                else if (f < DIN) r0 += xin[j * DIN + f];
            }
            float raw = xr + ((r0 + r1) + (r2 + r3));

            // fold input BN: (deg+1) rows each transformed a*v+b
            float hin = BN_IN ? fmaf(scale, raw, (float)(k1 - k0 + 1) * shift) : raw;

            // MLP layer 1: t1[f] = relu(b1[f] + sum_i hin_i * W1[i][f])
            float t1 = sb1[dir][f];
            #pragma unroll
            for (int i = 0; i < DIN; i++)
                t1 = fmaf(__shfl(hin, i, 32), sW1[dir][i * 32 + f], t1);
            t1 = fmaxf(t1, 0.f);

            // MLP layer 2
            float o2 = sb2[dir][f];
            #pragma unroll
            for (int i = 0; i < 32; i++)
                o2 = fmaf(__shfl(t1, i, 32), sW2[dir][i * 32 + f], o2);
            o += fmaxf(o2, 0.f);
        }
        o *= 0.5f;

        out[node * 32 + f] = o;             // raw (pre-BN) output, coalesced
        bn_s  += o;
        bn_s2 += o * o;
    }

    // BN stats of raw output: per-lane running sums -> LDS -> 64 global atomics
    atomicAdd(&sstat[f],      bn_s);
    atomicAdd(&sstat[32 + f], bn_s2);
    __syncthreads();
    if (tid < 64) atomicAdd(&stats[tid], sstat[tid]);
}

// ================= segmented mean-pool (batch is sorted) + head =============

__global__ void pool_seg(const float* __restrict__ h, const int* __restrict__ batch,
                         float* __restrict__ psum, float* __restrict__ pcnt, int n)
{
    int tid = threadIdx.x;
    int grp = tid >> 5, f = tid & 31;
    int base = blockIdx.x * 256;
    float acc = 0.f, cnt = 0.f;
    int curg = -1;
    for (int it = 0; it < 32; it++) {
        int nd = base + grp + it * 8;
        if (nd < n) {
            int g = batch[nd];
            if (g != curg) {
                if (curg >= 0) {
                    atomicAdd(&psum[curg * 32 + f], acc);
                    if (f == 0) atomicAdd(&pcnt[curg], cnt);
                }
                curg = g; acc = 0.f; cnt = 0.f;
            }
            acc += h[nd * 32 + f];
            cnt += 1.f;
        }
    }
    if (curg >= 0) {
        atomicAdd(&psum[curg * 32 + f], acc);
        if (f == 0) atomicAdd(&pcnt[curg], cnt);
    }
}

// head applies layer-3 BN to the pooled mean (mean of a*h+b = a*mean+b)

__global__ void head_kernel(const float* __restrict__ psum, const float* __restrict__ pcnt,
                            const float* __restrict__ stats3,
                            const float* __restrict__ g3, const float* __restrict__ b3,
                            const float* __restrict__ lbW, const float* __restrict__ lbb,
                            const float* __restrict__ lmW, const float* __restrict__ lmb,
                            float* __restrict__ out)
{
    int g = threadIdx.x;  // 512 threads, one block
    float cnt = fmaxf(pcnt[g], 1.0f);
    float inv = 1.0f / cnt;
    float p[32];
    #pragma unroll
    for (int i = 0; i < 32; i++) {
        float mu  = stats3[i] * INV_N;
        float var = stats3[32 + i] * INV_N - mu * mu;
        float a   = g3[i] * rsqrtf(var + BN_EPS);
        float b   = b3[i] - mu * a;
        p[i] = fmaf(a, psum[g * 32 + i] * inv, b);
    }
    float z = lmb[0];
    #pragma unroll
    for (int k = 0; k < 16; k++) {
        float acc = lbb[k];
        #pragma unroll
        for (int i = 0; i < 32; i++) acc += p[i] * lbW[i * 16 + k];
        z += fmaxf(acc, 0.0f) * lmW[k];
    }
    out[g] = 1.0f / (1.0f + expf(-z));
}

// ================= launcher =================================================

extern "C" void kernel_launch(void* const* d_in, const int* in_sizes, int n_in,
                              void* d_out, int out_size, void* d_ws, size_t ws_size,
                              hipStream_t stream)
{
    const float* x   = (const float*)d_in[0];
    const int* ei    = (const int*)d_in[1];
    const int* batch = (const int*)d_in[2];
    const int* src = ei;
    const int* dst = ei + N_EDGES;

    char* ws = (char*)d_ws;
    float* h_a    = (float*)(ws + 0);           // 32,000,000 B
    float* h_b    = (float*)(ws + 32000000);    // 32,000,000 B
    int*   eidx   = (int*)  (ws + 64000000);    // 20,000,000 B
    int*   off    = (int*)  (ws + 84000000);    // 2,000,004 B (NT+1 ints)
    int*   deg    = (int*)  (ws + 86000016);    // 2,000,000 B
    int*   cur    = (int*)  (ws + 88000016);    // 2,000,000 B
    int*   excl   = (int*)  (ws + 90000016);    // 2,000,000 B
    int*   bsum   = (int*)  (ws + 92000016);    // ~2 KB
    int*   boff   = (int*)  (ws + 92004016);    // ~2 KB
    float* stats1 = (float*)(ws + 92008016);    // 64 floats
    float* stats2 = (float*)(ws + 92008272);    // 64 floats
    float* stats3 = (float*)(ws + 92008528);    // 64 floats
    float* psum   = (float*)(ws + 92008784);    // 512*32 floats
    float* pcnt   = (float*)(ws + 92074320);    // 512 floats

    auto W = [&](int l, int j) { return (const float*)d_in[3 + (l - 1) * 10 + j]; };

    // ---- CSR build (both directions concatenated)
    hipMemsetAsync(deg, 0, NT * 4, stream);
    hipMemsetAsync(cur, 0, NT * 4, stream);
    k_deg<<<(N_EDGES + 255) / 256, 256, 0, stream>>>(src, dst, deg, N_EDGES);
    int nb = (NT + 1023) / 1024;  // 489
    scan1<<<nb, 256, 0, stream>>>(deg, excl, bsum, NT);
    scan2<<<1, 512, 0, stream>>>(bsum, boff, nb);
    scan3<<<(NT + 256) / 256, 256, 0, stream>>>(excl, boff, off, NT);
    k_fill<<<(N_EDGES + 255) / 256, 256, 0, stream>>>(src, dst, off, cur, eidx, N_EDGES);

    const int NGROUPS = N_NODES / 8;           // 31250 (exact)
    const int GRID_G  = 2048;                  // 8 blocks/CU resident

    hipMemsetAsync(stats1, 0, 64 * 4, stream);
    hipMemsetAsync(stats2, 0, 64 * 4, stream);
    hipMemsetAsync(stats3, 0, 64 * 4, stream);

    // ---- layer 1 (DIN=6, no input BN): x -> h_a (raw), stats1
    dgin_gather<6, false><<<GRID_G, 256, 0, stream>>>(
        x, off, eidx, nullptr, nullptr, nullptr,
        W(1,0), W(1,1), W(1,2), W(1,3), W(1,4), W(1,5), W(1,6), W(1,7),
        h_a, stats1, NGROUPS);

    // ---- layer 2: h_a (raw, BN1 folded) -> h_b (raw), stats2
    dgin_gather<32, true><<<GRID_G, 256, 0, stream>>>(
        h_a, off, eidx, stats1, W(1,8), W(1,9),
        W(2,0), W(2,1), W(2,2), W(2,3), W(2,4), W(2,5), W(2,6), W(2,7),
        h_b, stats2, NGROUPS);

    // ---- layer 3: h_b (raw, BN2 folded) -> h_a (raw), stats3
    dgin_gather<32, true><<<GRID_G, 256, 0, stream>>>(
        h_b, off, eidx, stats2, W(2,8), W(2,9),
        W(3,0), W(3,1), W(3,2), W(3,3), W(3,4), W(3,5), W(3,6), W(3,7),
        h_a, stats3, NGROUPS);

    // ---- pool raw h3 + head (BN3 folded into pooled mean)
    hipMemsetAsync(psum, 0, (size_t)N_GRAPHS * 32 * 4, stream);
    hipMemsetAsync(pcnt, 0, (size_t)N_GRAPHS * 4, stream);
    pool_seg<<<(N_NODES + 255) / 256, 256, 0, stream>>>(h_a, batch, psum, pcnt, N_NODES);
    head_kernel<<<1, 512, 0, stream>>>(psum, pcnt, stats3, W(3,8), W(3,9),
        (const float*)d_in[33], (const float*)d_in[34],
        (const float*)d_in[35], (const float*)d_in[36],
        (float*)d_out);
}